// Round 15
// baseline (403.862 us; speedup 1.0000x reference)
//
#include <hip/hip_runtime.h>
#include <hip/hip_bf16.h>

typedef __attribute__((ext_vector_type(4))) float f32x4;
typedef __attribute__((ext_vector_type(8))) short bf16x8;

#define M_DIM 8192
#define N_DIM 4096
#define K_DIM 4096
#define NH 8
#define R_DIM 16
#define HQ 128          // NH * R_DIM

__device__ __forceinline__ unsigned short f2bf(float f) {
  union { float f; unsigned int u; } v; v.f = f;
  unsigned int r = v.u + 0x7fffu + ((v.u >> 16) & 1u);  // RNE
  return (unsigned short)(r >> 16);
}

__device__ __forceinline__ void gll16(const void* gptr, void* lptr) {
  __builtin_amdgcn_global_load_lds(
      (const __attribute__((address_space(1))) void*)gptr,
      (__attribute__((address_space(3))) void*)lptr, 16, 0, 0);
}

__device__ __forceinline__ unsigned lds_addr(const void* p) {
  return (unsigned)(uintptr_t)(const __attribute__((address_space(3))) void*)p;
}

#define FENCE() asm volatile("" ::: "memory")
#define BAR() do { FENCE(); __builtin_amdgcn_s_barrier(); FENCE(); } while (0)
// counted lgkm wait + the rule-#18 minimum fence (sched_barrier right after)
#define LGKM(N) do { asm volatile("s_waitcnt lgkmcnt(" #N ")" ::: "memory"); \
  __builtin_amdgcn_sched_barrier(0); } while (0)
#define VMC(N) asm volatile("s_waitcnt vmcnt(" #N ")" ::: "memory")
#define DSR(D, ADDR, IMM) asm volatile("ds_read_b128 %0, %1 offset:%2" \
  : "=&v"(D) : "v"(ADDR), "i"(IMM))

// ---------------- Kernel 1: cast x (f32) -> bf16 ----------------
__global__ void k_cast_bf16(const float* __restrict__ in,
                            unsigned short* __restrict__ out, int n4) {
  int i = blockIdx.x * 256 + threadIdx.x;
  if (i >= n4) return;
  float4 v = reinterpret_cast<const float4*>(in)[i];
  ushort4 o;
  o.x = f2bf(v.x); o.y = f2bf(v.y); o.z = f2bf(v.z); o.w = f2bf(v.w);
  reinterpret_cast<ushort4*>(out)[i] = o;
}

// ---------------- Kernel 2a: HA_T[d][h*16+q] = bf16( s[h]*sum_r H[h][q][r]*A[h][r][d] )
__global__ void k_ha_t(const float* __restrict__ A, const float* __restrict__ H,
                       const float* __restrict__ s, unsigned short* __restrict__ HA_T) {
  const int d = blockIdx.x * 256 + threadIdx.x;
  const int h = blockIdx.y;
  const float* Ah = A + (size_t)h * R_DIM * K_DIM;
  const float* Hh = H + h * R_DIM * R_DIM;
  const float sv = s[h];
  float acc[R_DIM];
  #pragma unroll
  for (int q = 0; q < R_DIM; ++q) acc[q] = 0.f;
  #pragma unroll
  for (int r = 0; r < R_DIM; ++r) {
    float a = Ah[(size_t)r * K_DIM + d];
    #pragma unroll
    for (int q = 0; q < R_DIM; ++q) acc[q] += Hh[q * R_DIM + r] * a;
  }
  unsigned short o[R_DIM];
  #pragma unroll
  for (int q = 0; q < R_DIM; ++q) o[q] = f2bf(acc[q] * sv);
  *reinterpret_cast<uint4*>(&HA_T[(size_t)d * HQ + h * R_DIM]) = *reinterpret_cast<uint4*>(o);
  *reinterpret_cast<uint4*>(&HA_T[(size_t)d * HQ + h * R_DIM + 8]) = *reinterpret_cast<uint4*>(o + 8);
}

// ---------------- Kernel 2b: Bc[o][h*16+q] = bf16( B[h][o][q] ) ----------------
__global__ void k_bcat(const float* __restrict__ Bm, unsigned short* __restrict__ Bc) {
  const int t = threadIdx.x;
  const int ol = t >> 4, q = t & 15;
  const int o = blockIdx.x * 16 + ol;
  #pragma unroll
  for (int h = 0; h < NH; ++h)
    Bc[(size_t)o * HQ + h * R_DIM + q] = f2bf(Bm[((size_t)h * N_DIM + o) * R_DIM + q]);
}

// ---------------- Kernel 3: Weff = bf16(W + Bc @ HA_T^T), K=128 MFMA GEMM ----------------
__global__ __launch_bounds__(256)
void k_weff_mfma(const unsigned short* __restrict__ Ab,   // Bc [4096][128]
                 const unsigned short* __restrict__ Bb,   // HA_T [4096][128]
                 const float* __restrict__ W,
                 unsigned short* __restrict__ Weff) {
  constexpr int WK = HQ;  // 128
  __shared__ unsigned short As[128 * 32];
  __shared__ unsigned short Bs[128 * 32];

  const int t = threadIdx.x;
  const int lane = t & 63;
  const int wave = t >> 6;
  const int wr = wave >> 1, wc = wave & 1;
  const int brow = blockIdx.y * 128;
  const int bcol = blockIdx.x * 128;

  const int r0 = t >> 2, ch = t & 3;
  const size_t a_off0 = (size_t)(brow + r0) * WK + ch * 8;
  const size_t a_off1 = (size_t)(brow + r0 + 64) * WK + ch * 8;
  const size_t b_off0 = (size_t)(bcol + r0) * WK + ch * 8;
  const size_t b_off1 = (size_t)(bcol + r0 + 64) * WK + ch * 8;
  unsigned short* as_d0 = As + t * 8;
  unsigned short* as_d1 = As + (t + 256) * 8;
  unsigned short* bs_d0 = Bs + t * 8;
  unsigned short* bs_d1 = Bs + (t + 256) * 8;

  const int fr = lane & 15;
  const int kk = (lane >> 4) * 8;

  f32x4 acc[4][4] = {};

  for (int k0 = 0; k0 < WK; k0 += 32) {
    gll16(Ab + a_off0 + k0, as_d0);
    gll16(Ab + a_off1 + k0, as_d1);
    gll16(Bb + b_off0 + k0, bs_d0);
    gll16(Bb + b_off1 + k0, bs_d1);
    __syncthreads();

    bf16x8 af[4], bfr[4];
    #pragma unroll
    for (int m = 0; m < 4; ++m)
      af[m] = *reinterpret_cast<const bf16x8*>(&As[(wr * 64 + m * 16 + fr) * 32 + kk]);
    #pragma unroll
    for (int n = 0; n < 4; ++n)
      bfr[n] = *reinterpret_cast<const bf16x8*>(&Bs[(wc * 64 + n * 16 + fr) * 32 + kk]);

    #pragma unroll
    for (int m = 0; m < 4; ++m)
      #pragma unroll
      for (int n = 0; n < 4; ++n)
        acc[m][n] = __builtin_amdgcn_mfma_f32_16x16x32_bf16(af[m], bfr[n], acc[m][n], 0, 0, 0);

    __syncthreads();
  }

  const int crow0 = brow + wr * 64 + (lane >> 4) * 4;
  const int ccol0 = bcol + wc * 64 + fr;
  #pragma unroll
  for (int m = 0; m < 4; ++m)
    #pragma unroll
    for (int n = 0; n < 4; ++n) {
      const int col = ccol0 + n * 16;
      #pragma unroll
      for (int r = 0; r < 4; ++r) {
        const size_t idx = (size_t)(crow0 + m * 16 + r) * N_DIM + col;
        Weff[idx] = f2bf(acc[m][n][r] + W[idx]);
      }
    }
}

// ---------------- Kernel 4: 256x256 GEMM, R11 + reg-neutral pD read-prefetch --------
// R11 skeleton (slots, stage order, swizzle) with VMC moved pD->pC and tile T+1's
// arA'/bE' reads issued in pD, REUSING arA/bE (dead since pB/pC) — zero VGPR delta
// (the fix for R13's spill).  Every ds_read now drains under >=1 MFMA quad + BAR:
//  pA: issue bO(s1);        stage as3; LGKM(4)  [arA',bE' from pD: shadowed] Q00; BAR
//  pB: issue arB(s1);       stage as0; LGKM(8)  [drains bO, shadowed by Q00] Q01; BAR
//  pC:                      stage bs0; LGKM(0)  [drains arB, shadowed by Q01] Q10;
//      VMC(4); BAR   <- confirms {as2,bs2,bs3,as3} = everything pD..pB' read
//  pD: issue arA(s2),bE(s2); stage bs1; Q11 (operands long drained); BAR
// (odd tile mirrored on slots 2,3 / stages as1,as2,bs2,bs3; VMC(4)@pC' confirms
// {as0,bs0,bs1,as1}).  Restage >=1 barrier after each slot's reads drain (checked
// per slot); prologue hands off identical steady state (first-pC outstanding = 12).
__global__ __launch_bounds__(512, 2)
void k_gemm256(const unsigned short* __restrict__ A,
               const unsigned short* __restrict__ Bw,
               const float* __restrict__ bias,
               float* __restrict__ C) {
  __shared__ unsigned short As[4][128][64];  // 64 KB
  __shared__ unsigned short Bs[4][128][64];  // 64 KB
  constexpr int SLOT_E = 128 * 64;

  const int t    = threadIdx.x;
  const int lane = t & 63;
  const int wave = t >> 6;
  const int wr   = wave >> 2;
  const int wc   = wave & 3;
  const int fr   = lane & 15;
  const int kq   = lane >> 4;

  const int bid = blockIdx.x;
  const int swz = (bid & 7) * 64 + (bid >> 3);
  const int brow = (swz >> 4) * 256;
  const int bcol = (swz & 15) * 256;

  const unsigned short* Ag = A  + (size_t)brow * K_DIM;
  const unsigned short* Bg = Bw + (size_t)bcol * K_DIM;

  const int i0 = t, i1 = 512 + t;
  const int r_s0 = i0 >> 3, r_s1 = i1 >> 3;
  const int c_e0 = (((i0 & 7) * 16) ^ ((r_s0 & 7) << 4)) >> 1;
  const int c_e1 = (((i1 & 7) * 16) ^ ((r_s1 & 7) << 4)) >> 1;

  unsigned short* as0 = &As[0][0][0];
  unsigned short* bs0 = &Bs[0][0][0];

  const int arow  = wr * 64 + fr;
  const int browl = wc * 32 + fr;
  const int axr   = (fr & 7) << 4;
  const unsigned colx0 = (unsigned)((kq * 16) ^ axr);
  const unsigned colx1 = (unsigned)((kq * 16 + 64) ^ axr);
  const unsigned aK0 = lds_addr(as0) + arow * 128 + colx0;
  const unsigned aK1 = lds_addr(as0) + arow * 128 + colx1;
  const unsigned bK0 = lds_addr(bs0) + browl * 128 + colx0;
  const unsigned bK1 = lds_addr(bs0) + browl * 128 + colx1;

#define STAGE(DST, GBASE, T_, H_) do { \
    gll16((GBASE) + (size_t)((H_) * 128 + r_s0) * K_DIM + (T_) * 64 + c_e0, (DST) + i0 * 8); \
    gll16((GBASE) + (size_t)((H_) * 128 + r_s1) * K_DIM + (T_) * 64 + c_e1, (DST) + i1 * 8); \
  } while (0)

#define RA_(AR, S) do { \
    DSR(AR[0][0], aK0, (S)*16384 + 0*2048); DSR(AR[0][1], aK1, (S)*16384 + 0*2048); \
    DSR(AR[1][0], aK0, (S)*16384 + 1*2048); DSR(AR[1][1], aK1, (S)*16384 + 1*2048); \
    DSR(AR[2][0], aK0, (S)*16384 + 2*2048); DSR(AR[2][1], aK1, (S)*16384 + 2*2048); \
    DSR(AR[3][0], aK0, (S)*16384 + 3*2048); DSR(AR[3][1], aK1, (S)*16384 + 3*2048); \
  } while (0)

#define RB_(BR, S) do { \
    DSR(BR[0][0], bK0, (S)*16384 + 0*2048); DSR(BR[0][1], bK1, (S)*16384 + 0*2048); \
    DSR(BR[1][0], bK0, (S)*16384 + 1*2048); DSR(BR[1][1], bK1, (S)*16384 + 1*2048); \
  } while (0)

#define QUAD(MH, NHX, AR, BR) do { \
    __builtin_amdgcn_s_setprio(1); \
    _Pragma("unroll") for (int m = 0; m < 4; ++m) \
    _Pragma("unroll") for (int n = 0; n < 2; ++n) \
    _Pragma("unroll") for (int ks = 0; ks < 2; ++ks) \
      acc[MH][NHX][m][n] = __builtin_amdgcn_mfma_f32_16x16x32_bf16(AR[m][ks], BR[n][ks], acc[MH][NHX][m][n], 0, 0, 0); \
    __builtin_amdgcn_s_setprio(0); \
  } while (0)

  bf16x8 arA[4][2], arB[4][2];   // A fragment ping-pong (half0 / half1)
  bf16x8 bE[2][2],  bO[2][2];    // B fragment ping-pong
  f32x4 acc[2][2][4][2] = {};

  // ---- prologue: tile0 fully + tile1 (A0,B0,B1) — R11-identical; preload arA,bE.
  STAGE(as0 + 0 * SLOT_E, Ag, 0, 0);
  STAGE(bs0 + 0 * SLOT_E, Bg, 0, 0);
  STAGE(bs0 + 1 * SLOT_E, Bg, 0, 1);
  STAGE(as0 + 1 * SLOT_E, Ag, 0, 1);
  STAGE(as0 + 2 * SLOT_E, Ag, 1, 0);
  STAGE(bs0 + 2 * SLOT_E, Bg, 1, 0);
  STAGE(bs0 + 3 * SLOT_E, Bg, 1, 1);
  VMC(6);                         // tile0's 4 half-tiles confirmed
  BAR();
  RA_(arA, 0); RB_(bE, 0);        // tile0 Q00 operands in flight

  #pragma unroll 1
  for (int it = 0; it < 31; ++it) {
    const int T = 2 * it;
    // ---- tile T (even, slots 0,1)
    // pA
    RB_(bO, 1);
    STAGE(as0 + 3 * SLOT_E, Ag, T + 1, 1);
    LGKM(4);  QUAD(0, 0, arA, bE);  BAR();
    // pB
    RA_(arB, 1);
    STAGE(as0 + 0 * SLOT_E, Ag, T + 2, 0);
    LGKM(8);  QUAD(0, 1, arA, bO);  BAR();
    // pC (counted global drain: confirms {as2,bs2,bs3,as3})
    STAGE(bs0 + 0 * SLOT_E, Bg, T + 2, 0);
    LGKM(0);  QUAD(1, 0, arB, bE);
    VMC(4);
    BAR();
    // pD: prefetch tile T+1's arA/bE (register-neutral: both dead), drain under Q11
    RA_(arA, 2); RB_(bE, 2);
    STAGE(bs0 + 1 * SLOT_E, Bg, T + 2, 1);
    QUAD(1, 1, arB, bO);
    BAR();
    // ---- tile T+1 (odd, slots 2,3)
    // pA'
    RB_(bO, 3);
    STAGE(as0 + 1 * SLOT_E, Ag, T + 2, 1);
    LGKM(4);  QUAD(0, 0, arA, bE);  BAR();
    // pB'
    RA_(arB, 3);
    STAGE(as0 + 2 * SLOT_E, Ag, T + 3, 0);
    LGKM(8);  QUAD(0, 1, arA, bO);  BAR();
    // pC' (confirms {as0,bs0,bs1,as1})
    STAGE(bs0 + 2 * SLOT_E, Bg, T + 3, 0);
    LGKM(0);  QUAD(1, 0, arB, bE);
    VMC(4);
    BAR();
    // pD': prefetch tile T+2's arA/bE from slots 0
    RA_(arA, 0); RB_(bE, 0);
    STAGE(bs0 + 3 * SLOT_E, Bg, T + 3, 1);
    QUAD(1, 1, arB, bO);
    BAR();
  }

  // ---- epilogue: tiles 62 (slots 0,1) and 63 (slots 2,3); arA/bE for 62 in flight.
  STAGE(as0 + 3 * SLOT_E, Ag, 63, 1);
  VMC(0);
  BAR();
  // tile 62
  RB_(bO, 1);
  LGKM(4);  QUAD(0, 0, arA, bE);
  RA_(arB, 1);
  LGKM(8);  QUAD(0, 1, arA, bO);
  LGKM(0);  QUAD(1, 0, arB, bE);
  RA_(arA, 2); RB_(bE, 2);
  QUAD(1, 1, arB, bO);
  // tile 63
  RB_(bO, 3);
  LGKM(4);  QUAD(0, 0, arA, bE);
  RA_(arB, 3);
  LGKM(8);  QUAD(0, 1, arA, bO);
  LGKM(0);  QUAD(1, 0, arB, bE);
  QUAD(1, 1, arB, bO);

#undef STAGE
#undef RA_
#undef RB_
#undef QUAD

  // ---- C write: C/D layout col=lane&15, row=4*(lane>>4)+reg (m89-verified)
  const int crow = brow + wr * 64 + kq * 4;
  const int ccol = bcol + wc * 32 + fr;
  #pragma unroll
  for (int mh = 0; mh < 2; ++mh)
  #pragma unroll
  for (int nh = 0; nh < 2; ++nh)
  #pragma unroll
  for (int m = 0; m < 4; ++m)
  #pragma unroll
  for (int n = 0; n < 2; ++n) {
    const int col = ccol + nh * 128 + n * 16;
    const float bv = bias[col];
    #pragma unroll
    for (int r = 0; r < 4; ++r)
      C[(size_t)(crow + mh * 128 + m * 16 + r) * N_DIM + col] = acc[mh][nh][m][n][r] + bv;
  }
}

// ---------------- launch ----------------
extern "C" void kernel_launch(void* const* d_in, const int* in_sizes, int n_in,
                              void* d_out, int out_size, void* d_ws, size_t ws_size,
                              hipStream_t stream) {
  const float* x  = (const float*)d_in[0];
  const float* W  = (const float*)d_in[1];
  const float* bv = (const float*)d_in[2];
  const float* Am = (const float*)d_in[3];
  const float* Hm = (const float*)d_in[4];
  const float* Bm = (const float*)d_in[5];
  const float* sv = (const float*)d_in[6];
  float* out = (float*)d_out;

  char* ws = (char*)d_ws;
  unsigned short* xbf  = (unsigned short*)ws;                                 // 64 MB
  unsigned short* weff = (unsigned short*)(ws + (size_t)M_DIM * K_DIM * 2);   // 32 MB
  unsigned short* hat  = (unsigned short*)(ws + (size_t)(M_DIM + N_DIM) * K_DIM * 2);          // 1 MB
  unsigned short* bc   = (unsigned short*)(ws + (size_t)(M_DIM + N_DIM) * K_DIM * 2 + (size_t)N_DIM * HQ * 2); // 1 MB

  k_cast_bf16<<<(M_DIM * K_DIM / 4 + 255) / 256, 256, 0, stream>>>(x, xbf, M_DIM * K_DIM / 4);
  k_ha_t<<<dim3(K_DIM / 256, NH), 256, 0, stream>>>(Am, Hm, sv, hat);
  k_bcat<<<N_DIM / 16, 256, 0, stream>>>(Bm, bc);
  k_weff_mfma<<<dim3(N_DIM / 128, N_DIM / 128), 256, 0, stream>>>(bc, hat, W, weff);
  k_gemm256<<<dim3(512), 512, 0, stream>>>(xbf, weff, bv, out);
}

// Round 16
// 287.930 us; speedup vs baseline: 1.4026x; 1.4026x over previous
//
#include <hip/hip_runtime.h>
#include <hip/hip_bf16.h>

typedef __attribute__((ext_vector_type(4))) float f32x4;
typedef __attribute__((ext_vector_type(8))) short bf16x8;

#define M_DIM 8192
#define N_DIM 4096
#define K_DIM 4096
#define NH 8
#define R_DIM 16
#define HQ 128          // NH * R_DIM

__device__ __forceinline__ unsigned short f2bf(float f) {
  union { float f; unsigned int u; } v; v.f = f;
  unsigned int r = v.u + 0x7fffu + ((v.u >> 16) & 1u);  // RNE
  return (unsigned short)(r >> 16);
}

__device__ __forceinline__ void gll16(const void* gptr, void* lptr) {
  __builtin_amdgcn_global_load_lds(
      (const __attribute__((address_space(1))) void*)gptr,
      (__attribute__((address_space(3))) void*)lptr, 16, 0, 0);
}

__device__ __forceinline__ unsigned lds_addr(const void* p) {
  return (unsigned)(uintptr_t)(const __attribute__((address_space(3))) void*)p;
}

#define FENCE() asm volatile("" ::: "memory")
#define BAR() do { FENCE(); __builtin_amdgcn_s_barrier(); FENCE(); } while (0)
// counted lgkm wait + the rule-#18 minimum fence (sched_barrier right after)
#define LGKM(N) do { asm volatile("s_waitcnt lgkmcnt(" #N ")" ::: "memory"); \
  __builtin_amdgcn_sched_barrier(0); } while (0)
#define VMC(N) asm volatile("s_waitcnt vmcnt(" #N ")" ::: "memory")
#define DSR(D, ADDR, IMM) asm volatile("ds_read_b128 %0, %1 offset:%2" \
  : "=&v"(D) : "v"(ADDR), "i"(IMM))

// ---------------- Kernel 1: cast x (f32) -> bf16 ----------------
__global__ void k_cast_bf16(const float* __restrict__ in,
                            unsigned short* __restrict__ out, int n4) {
  int i = blockIdx.x * 256 + threadIdx.x;
  if (i >= n4) return;
  float4 v = reinterpret_cast<const float4*>(in)[i];
  ushort4 o;
  o.x = f2bf(v.x); o.y = f2bf(v.y); o.z = f2bf(v.z); o.w = f2bf(v.w);
  reinterpret_cast<ushort4*>(out)[i] = o;
}

// ---------------- Kernel 2: merged prep ----------------
// blocks 0..127:   HA_T[d][h*16+q] = bf16( s[h]*sum_r H[h][q][r]*A[h][r][d] )
// blocks 128..383: Bc[o][h*16+q]   = bf16( B[h][o][q] )
__global__ void k_prep(const float* __restrict__ A, const float* __restrict__ H,
                       const float* __restrict__ s, const float* __restrict__ Bm,
                       unsigned short* __restrict__ HA_T, unsigned short* __restrict__ Bc) {
  const int bid = blockIdx.x;
  const int t = threadIdx.x;
  if (bid < 128) {
    const int d = (bid & 15) * 256 + t;
    const int h = bid >> 4;
    const float* Ah = A + (size_t)h * R_DIM * K_DIM;
    const float* Hh = H + h * R_DIM * R_DIM;
    const float sv = s[h];
    float acc[R_DIM];
    #pragma unroll
    for (int q = 0; q < R_DIM; ++q) acc[q] = 0.f;
    #pragma unroll
    for (int r = 0; r < R_DIM; ++r) {
      float a = Ah[(size_t)r * K_DIM + d];
      #pragma unroll
      for (int q = 0; q < R_DIM; ++q) acc[q] += Hh[q * R_DIM + r] * a;
    }
    unsigned short o[R_DIM];
    #pragma unroll
    for (int q = 0; q < R_DIM; ++q) o[q] = f2bf(acc[q] * sv);
    *reinterpret_cast<uint4*>(&HA_T[(size_t)d * HQ + h * R_DIM]) = *reinterpret_cast<uint4*>(o);
    *reinterpret_cast<uint4*>(&HA_T[(size_t)d * HQ + h * R_DIM + 8]) = *reinterpret_cast<uint4*>(o + 8);
  } else {
    const int o = (bid - 128) * 16 + (t >> 4);
    const int q = t & 15;
    #pragma unroll
    for (int h = 0; h < NH; ++h)
      Bc[(size_t)o * HQ + h * R_DIM + q] = f2bf(Bm[((size_t)h * N_DIM + o) * R_DIM + q]);
  }
}

// ---------------- Kernel 3: Weff = bf16(W + Bc @ HA_T^T), K=128 MFMA GEMM ----------------
__global__ __launch_bounds__(256)
void k_weff_mfma(const unsigned short* __restrict__ Ab,   // Bc [4096][128]
                 const unsigned short* __restrict__ Bb,   // HA_T [4096][128]
                 const float* __restrict__ W,
                 unsigned short* __restrict__ Weff) {
  constexpr int WK = HQ;  // 128
  __shared__ unsigned short As[128 * 32];
  __shared__ unsigned short Bs[128 * 32];

  const int t = threadIdx.x;
  const int lane = t & 63;
  const int wave = t >> 6;
  const int wr = wave >> 1, wc = wave & 1;
  const int brow = blockIdx.y * 128;
  const int bcol = blockIdx.x * 128;

  const int r0 = t >> 2, ch = t & 3;
  const size_t a_off0 = (size_t)(brow + r0) * WK + ch * 8;
  const size_t a_off1 = (size_t)(brow + r0 + 64) * WK + ch * 8;
  const size_t b_off0 = (size_t)(bcol + r0) * WK + ch * 8;
  const size_t b_off1 = (size_t)(bcol + r0 + 64) * WK + ch * 8;
  unsigned short* as_d0 = As + t * 8;
  unsigned short* as_d1 = As + (t + 256) * 8;
  unsigned short* bs_d0 = Bs + t * 8;
  unsigned short* bs_d1 = Bs + (t + 256) * 8;

  const int fr = lane & 15;
  const int kk = (lane >> 4) * 8;

  f32x4 acc[4][4] = {};

  for (int k0 = 0; k0 < WK; k0 += 32) {
    gll16(Ab + a_off0 + k0, as_d0);
    gll16(Ab + a_off1 + k0, as_d1);
    gll16(Bb + b_off0 + k0, bs_d0);
    gll16(Bb + b_off1 + k0, bs_d1);
    __syncthreads();

    bf16x8 af[4], bfr[4];
    #pragma unroll
    for (int m = 0; m < 4; ++m)
      af[m] = *reinterpret_cast<const bf16x8*>(&As[(wr * 64 + m * 16 + fr) * 32 + kk]);
    #pragma unroll
    for (int n = 0; n < 4; ++n)
      bfr[n] = *reinterpret_cast<const bf16x8*>(&Bs[(wc * 64 + n * 16 + fr) * 32 + kk]);

    #pragma unroll
    for (int m = 0; m < 4; ++m)
      #pragma unroll
      for (int n = 0; n < 4; ++n)
        acc[m][n] = __builtin_amdgcn_mfma_f32_16x16x32_bf16(af[m], bfr[n], acc[m][n], 0, 0, 0);

    __syncthreads();
  }

  const int crow0 = brow + wr * 64 + (lane >> 4) * 4;
  const int ccol0 = bcol + wc * 64 + fr;
  #pragma unroll
  for (int m = 0; m < 4; ++m)
    #pragma unroll
    for (int n = 0; n < 4; ++n) {
      const int col = ccol0 + n * 16;
      #pragma unroll
      for (int r = 0; r < 4; ++r) {
        const size_t idx = (size_t)(crow0 + m * 16 + r) * N_DIM + col;
        Weff[idx] = f2bf(acc[m][n][r] + W[idx]);
      }
    }
}

// ---------------- Kernel 4: 256x256 GEMM — R11 verified optimum ----------------
// 4 phases/tile, deferred sub-group reads with counted lgkm, all reads issued and
// drained WITHIN their phase (cross-barrier in-flight ds_reads regress 45%+ on this
// chip: R4/R7/R13/R15).  Slots per operand: 4 x [128][64]; tile T half h -> slot
// (T&1)*2+h.  pA: reads arA,bE,bO (16), LGKM(4) -> Q00 (bO flies under Q00);
// pB: reads arB (8), LGKM(8) -> Q01 (arB flies); pC: LGKM(0) -> Q10;
// pD: Q11, VMC(6) (confirms tile T+1), BAR.  Stage order as3,as0,bs0,bs1 |
// as1,as2,bs2,bs3; every restage >=1 barrier after that slot's reads drain.
__global__ __launch_bounds__(512, 2)
void k_gemm256(const unsigned short* __restrict__ A,
               const unsigned short* __restrict__ Bw,
               const float* __restrict__ bias,
               float* __restrict__ C) {
  __shared__ unsigned short As[4][128][64];  // 64 KB
  __shared__ unsigned short Bs[4][128][64];  // 64 KB
  constexpr int SLOT_E = 128 * 64;

  const int t    = threadIdx.x;
  const int lane = t & 63;
  const int wave = t >> 6;
  const int wr   = wave >> 2;
  const int wc   = wave & 3;
  const int fr   = lane & 15;
  const int kq   = lane >> 4;

  const int bid = blockIdx.x;
  const int swz = (bid & 7) * 64 + (bid >> 3);
  const int brow = (swz >> 4) * 256;
  const int bcol = (swz & 15) * 256;

  const unsigned short* Ag = A  + (size_t)brow * K_DIM;
  const unsigned short* Bg = Bw + (size_t)bcol * K_DIM;

  const int i0 = t, i1 = 512 + t;
  const int r_s0 = i0 >> 3, r_s1 = i1 >> 3;
  const int c_e0 = (((i0 & 7) * 16) ^ ((r_s0 & 7) << 4)) >> 1;
  const int c_e1 = (((i1 & 7) * 16) ^ ((r_s1 & 7) << 4)) >> 1;

  unsigned short* as0 = &As[0][0][0];
  unsigned short* bs0 = &Bs[0][0][0];

  const int arow  = wr * 64 + fr;
  const int browl = wc * 32 + fr;
  const int axr   = (fr & 7) << 4;
  const unsigned colx0 = (unsigned)((kq * 16) ^ axr);
  const unsigned colx1 = (unsigned)((kq * 16 + 64) ^ axr);
  const unsigned aK0 = lds_addr(as0) + arow * 128 + colx0;
  const unsigned aK1 = lds_addr(as0) + arow * 128 + colx1;
  const unsigned bK0 = lds_addr(bs0) + browl * 128 + colx0;
  const unsigned bK1 = lds_addr(bs0) + browl * 128 + colx1;

#define STAGE(DST, GBASE, T_, H_) do { \
    gll16((GBASE) + (size_t)((H_) * 128 + r_s0) * K_DIM + (T_) * 64 + c_e0, (DST) + i0 * 8); \
    gll16((GBASE) + (size_t)((H_) * 128 + r_s1) * K_DIM + (T_) * 64 + c_e1, (DST) + i1 * 8); \
  } while (0)

#define RA_(AR, S) do { \
    DSR(AR[0][0], aK0, (S)*16384 + 0*2048); DSR(AR[0][1], aK1, (S)*16384 + 0*2048); \
    DSR(AR[1][0], aK0, (S)*16384 + 1*2048); DSR(AR[1][1], aK1, (S)*16384 + 1*2048); \
    DSR(AR[2][0], aK0, (S)*16384 + 2*2048); DSR(AR[2][1], aK1, (S)*16384 + 2*2048); \
    DSR(AR[3][0], aK0, (S)*16384 + 3*2048); DSR(AR[3][1], aK1, (S)*16384 + 3*2048); \
  } while (0)

#define RB_(BR, S) do { \
    DSR(BR[0][0], bK0, (S)*16384 + 0*2048); DSR(BR[0][1], bK1, (S)*16384 + 0*2048); \
    DSR(BR[1][0], bK0, (S)*16384 + 1*2048); DSR(BR[1][1], bK1, (S)*16384 + 1*2048); \
  } while (0)

#define QUAD(MH, NHX, AR, BR) do { \
    __builtin_amdgcn_s_setprio(1); \
    _Pragma("unroll") for (int m = 0; m < 4; ++m) \
    _Pragma("unroll") for (int n = 0; n < 2; ++n) \
    _Pragma("unroll") for (int ks = 0; ks < 2; ++ks) \
      acc[MH][NHX][m][n] = __builtin_amdgcn_mfma_f32_16x16x32_bf16(AR[m][ks], BR[n][ks], acc[MH][NHX][m][n], 0, 0, 0); \
    __builtin_amdgcn_s_setprio(0); \
  } while (0)

  bf16x8 arA[4][2], arB[4][2];   // A fragment ping-pong (half0 / half1)
  bf16x8 bE[2][2],  bO[2][2];    // B fragment ping-pong
  f32x4 acc[2][2][4][2] = {};

  // ---- prologue: tile0 fully + tile1 (A0,B0,B1)
  STAGE(as0 + 0 * SLOT_E, Ag, 0, 0);
  STAGE(bs0 + 0 * SLOT_E, Bg, 0, 0);
  STAGE(bs0 + 1 * SLOT_E, Bg, 0, 1);
  STAGE(as0 + 1 * SLOT_E, Ag, 0, 1);
  STAGE(as0 + 2 * SLOT_E, Ag, 1, 0);
  STAGE(bs0 + 2 * SLOT_E, Bg, 1, 0);
  STAGE(bs0 + 3 * SLOT_E, Bg, 1, 1);
  VMC(6);                         // tile0's 4 half-tiles confirmed
  BAR();

  #pragma unroll 1
  for (int it = 0; it < 31; ++it) {
    const int T = 2 * it;
    // ---- tile T (even, slots 0,1)
    // pA
    RA_(arA, 0); RB_(bE, 0); RB_(bO, 1);
    STAGE(as0 + 3 * SLOT_E, Ag, T + 1, 1);
    LGKM(4);  QUAD(0, 0, arA, bE);  BAR();
    // pB
    RA_(arB, 1);
    STAGE(as0 + 0 * SLOT_E, Ag, T + 2, 0);
    LGKM(8);  QUAD(0, 1, arA, bO);  BAR();
    // pC
    STAGE(bs0 + 0 * SLOT_E, Bg, T + 2, 0);
    LGKM(0);  QUAD(1, 0, arB, bE);  BAR();
    // pD + counted global drain
    STAGE(bs0 + 1 * SLOT_E, Bg, T + 2, 1);
    QUAD(1, 1, arB, bO);
    VMC(6);
    BAR();
    // ---- tile T+1 (odd, slots 2,3)
    // pA'
    RA_(arA, 2); RB_(bE, 2); RB_(bO, 3);
    STAGE(as0 + 1 * SLOT_E, Ag, T + 2, 1);
    LGKM(4);  QUAD(0, 0, arA, bE);  BAR();
    // pB'
    RA_(arB, 3);
    STAGE(as0 + 2 * SLOT_E, Ag, T + 3, 0);
    LGKM(8);  QUAD(0, 1, arA, bO);  BAR();
    // pC'
    STAGE(bs0 + 2 * SLOT_E, Bg, T + 3, 0);
    LGKM(0);  QUAD(1, 0, arB, bE);  BAR();
    // pD' + counted global drain
    STAGE(bs0 + 3 * SLOT_E, Bg, T + 3, 1);
    QUAD(1, 1, arB, bO);
    VMC(6);
    BAR();
  }

  // ---- epilogue: tiles 62 (slots 0,1) and 63 (slots 2,3)
  STAGE(as0 + 3 * SLOT_E, Ag, 63, 1);
  VMC(0);
  BAR();
  // tile 62
  RA_(arA, 0); RB_(bE, 0); RB_(bO, 1); RA_(arB, 1);
  LGKM(12); QUAD(0, 0, arA, bE);
  LGKM(8);  QUAD(0, 1, arA, bO);
  LGKM(0);  QUAD(1, 0, arB, bE);
            QUAD(1, 1, arB, bO);
  // tile 63
  RA_(arA, 2); RB_(bE, 2); RB_(bO, 3); RA_(arB, 3);
  LGKM(12); QUAD(0, 0, arA, bE);
  LGKM(8);  QUAD(0, 1, arA, bO);
  LGKM(0);  QUAD(1, 0, arB, bE);
            QUAD(1, 1, arB, bO);

#undef STAGE
#undef RA_
#undef RB_
#undef QUAD

  // ---- C write: C/D layout col=lane&15, row=4*(lane>>4)+reg (m89-verified)
  const int crow = brow + wr * 64 + kq * 4;
  const int ccol = bcol + wc * 32 + fr;
  #pragma unroll
  for (int mh = 0; mh < 2; ++mh)
  #pragma unroll
  for (int nh = 0; nh < 2; ++nh)
  #pragma unroll
  for (int m = 0; m < 4; ++m)
  #pragma unroll
  for (int n = 0; n < 2; ++n) {
    const int col = ccol + nh * 128 + n * 16;
    const float bv = bias[col];
    #pragma unroll
    for (int r = 0; r < 4; ++r)
      C[(size_t)(crow + mh * 128 + m * 16 + r) * N_DIM + col] = acc[mh][nh][m][n][r] + bv;
  }
}

// ---------------- launch ----------------
extern "C" void kernel_launch(void* const* d_in, const int* in_sizes, int n_in,
                              void* d_out, int out_size, void* d_ws, size_t ws_size,
                              hipStream_t stream) {
  const float* x  = (const float*)d_in[0];
  const float* W  = (const float*)d_in[1];
  const float* bv = (const float*)d_in[2];
  const float* Am = (const float*)d_in[3];
  const float* Hm = (const float*)d_in[4];
  const float* Bm = (const float*)d_in[5];
  const float* sv = (const float*)d_in[6];
  float* out = (float*)d_out;

  char* ws = (char*)d_ws;
  unsigned short* xbf  = (unsigned short*)ws;                                 // 64 MB
  unsigned short* weff = (unsigned short*)(ws + (size_t)M_DIM * K_DIM * 2);   // 32 MB
  unsigned short* hat  = (unsigned short*)(ws + (size_t)(M_DIM + N_DIM) * K_DIM * 2);          // 1 MB
  unsigned short* bc   = (unsigned short*)(ws + (size_t)(M_DIM + N_DIM) * K_DIM * 2 + (size_t)N_DIM * HQ * 2); // 1 MB

  k_cast_bf16<<<(M_DIM * K_DIM / 4 + 255) / 256, 256, 0, stream>>>(x, xbf, M_DIM * K_DIM / 4);
  k_prep<<<384, 256, 0, stream>>>(Am, Hm, sv, Bm, hat, bc);
  k_weff_mfma<<<dim3(N_DIM / 128, N_DIM / 128), 256, 0, stream>>>(bc, hat, W, weff);
  k_gemm256<<<dim3(512), 512, 0, stream>>>(xbf, weff, bv, out);
}